// Round 1
// baseline (2730.786 us; speedup 1.0000x reference)
//
#include <hip/hip_runtime.h>
#include <math.h>

#define B_ 1024
#define D_ 2048
#define M_ 32
#define H_ 32

#define DBLK 8         // d-columns per block
#define BBLK 64        // b-rows per block
#define RPT  2         // b-rows per thread
#define WSTRIDE 1028   // 1024 + 4 pad: d-stride in LDS floats, 4d mod 32 bank offset

// Abramowitz & Stegun 7.1.26, |err| <= 1.5e-7 absolute. Uses hw rcp + exp.
__device__ __forceinline__ float fast_erff(float x) {
    float ax = fabsf(x);
    float t  = __builtin_amdgcn_rcpf(1.0f + 0.3275911f * ax);
    float p  = 1.061405429f;
    p = p * t - 1.453152027f;
    p = p * t + 1.421413741f;
    p = p * t - 0.284496736f;
    p = p * t + 0.254829592f;
    float e = __expf(-ax * ax);
    float r = 1.0f - p * t * e;
    return copysignf(r, x);
}

__global__ __launch_bounds__(256, 3)
void nlm_kernel(const float* __restrict__ pre,
                const float* __restrict__ w1,
                const float* __restrict__ b1,
                const float* __restrict__ w_out,
                const float* __restrict__ b_out,
                float* __restrict__ out) {
    __shared__ float w_lds[DBLK * WSTRIDE];   // 32.9 KB
    __shared__ float b1_lds[DBLK * 33];
    __shared__ float wo_lds[DBLK * 33];
    __shared__ float bo_lds[DBLK];

    const int tid = threadIdx.x;
    const int bx  = blockIdx.x;
    const int dt  = bx & (D_ / DBLK - 1);   // 0..255 — consecutive blocks walk d: contiguous HBM
    const int bt  = bx / (D_ / DBLK);       // 0..15
    const int d0  = dt * DBLK;
    const int b0  = bt * BBLK;

    // ---- stage w1 tile: 8 rows of 1024 floats, coalesced float4 ----
#pragma unroll
    for (int i = 0; i < DBLK; ++i) {
        const float4 v = *reinterpret_cast<const float4*>(
            w1 + (size_t)(d0 + i) * (H_ * M_) + tid * 4);
        *reinterpret_cast<float4*>(&w_lds[i * WSTRIDE + tid * 4]) = v;
    }
    {   // b1, w_out: 256 floats each; b_out: 8
        const int di = tid >> 5, h = tid & 31;
        b1_lds[di * 33 + h] = b1[(size_t)(d0 + di) * H_ + h];
        wo_lds[di * 33 + h] = w_out[(size_t)(d0 + di) * H_ + h];
        if (tid < DBLK) bo_lds[tid] = b_out[d0 + tid];
    }
    __syncthreads();

    const int d_local = tid & (DBLK - 1);
    const int bp      = tid >> 3;            // 0..31
    const int b_base  = b0 + bp * RPT;
    const int d       = d0 + d_local;

    const float* row0 = pre + ((size_t)b_base * D_ + d) * M_;
    const float* row1 = row0 + (size_t)D_ * M_;   // next b, same d

    float acc0[H_], acc1[H_];
#pragma unroll
    for (int h = 0; h < H_; ++h) { acc0[h] = 0.f; acc1[h] = 0.f; }

#pragma unroll
    for (int mg = 0; mg < M_ / 4; ++mg) {
        const float4 r0 = *reinterpret_cast<const float4*>(row0 + mg * 4);
        const float4 r1 = *reinterpret_cast<const float4*>(row1 + mg * 4);
#pragma unroll
        for (int h = 0; h < H_; ++h) {
            const float4 w = *reinterpret_cast<const float4*>(
                &w_lds[d_local * WSTRIDE + h * M_ + mg * 4]);
            acc0[h] += r0.x * w.x + r0.y * w.y + r0.z * w.z + r0.w * w.w;
            acc1[h] += r1.x * w.x + r1.y * w.y + r1.z * w.z + r1.w * w.w;
        }
    }

    // ---- epilogue: bias + exact-erf GELU + output dot + tanh ----
    float s0 = 0.f, s1 = 0.f;
#pragma unroll
    for (int h = 0; h < H_; ++h) {
        const float bb = b1_lds[d_local * 33 + h];
        const float wo = wo_lds[d_local * 33 + h];
        const float x0 = acc0[h] + bb;
        const float x1 = acc1[h] + bb;
        const float g0 = 0.5f * x0 * (1.0f + fast_erff(x0 * 0.70710678118f));
        const float g1 = 0.5f * x1 * (1.0f + fast_erff(x1 * 0.70710678118f));
        s0 += g0 * wo;
        s1 += g1 * wo;
    }
    const float bo = bo_lds[d_local];
    out[(size_t)b_base * D_ + d]           = tanhf(s0 + bo);
    out[(size_t)(b_base + 1) * D_ + d]     = tanhf(s1 + bo);
}

extern "C" void kernel_launch(void* const* d_in, const int* in_sizes, int n_in,
                              void* d_out, int out_size, void* d_ws, size_t ws_size,
                              hipStream_t stream) {
    const float* pre   = (const float*)d_in[0];
    const float* w1    = (const float*)d_in[1];
    const float* b1    = (const float*)d_in[2];
    const float* w_out = (const float*)d_in[3];
    const float* b_out = (const float*)d_in[4];
    float* out = (float*)d_out;

    const int grid = (D_ / DBLK) * (B_ / BBLK);   // 256 * 16 = 4096
    nlm_kernel<<<dim3(grid), dim3(256), 0, stream>>>(pre, w1, b1, w_out, b_out, out);
}

// Round 2
// 110.309 us; speedup vs baseline: 24.7558x; 24.7558x over previous
//
#include <hip/hip_runtime.h>
#include <math.h>

#define B_ 1024
#define D_ 2048
#define M_ 32
#define H_ 32

#define DBLK 8         // d-columns per block
#define BBLK 64        // b-rows per block
#define RPT  2         // b-rows per thread
#define WSTRIDE 1028   // 1024 + 4 pad: d-stride in LDS floats -> banks 4*d mod 32, conflict-free

// Abramowitz & Stegun 7.1.26, |err| <= 1.5e-7 absolute. Uses hw rcp + exp.
__device__ __forceinline__ float fast_erff(float x) {
    float ax = fabsf(x);
    float t  = __builtin_amdgcn_rcpf(1.0f + 0.3275911f * ax);
    float p  = 1.061405429f;
    p = p * t - 1.453152027f;
    p = p * t + 1.421413741f;
    p = p * t - 0.284496736f;
    p = p * t + 0.254829592f;
    float e = __expf(-ax * ax);
    float r = 1.0f - p * t * e;
    return copysignf(r, x);
}

__device__ __forceinline__ float gelu_exact(float x) {
    return 0.5f * x * (1.0f + fast_erff(x * 0.70710678118f));
}

__global__ __launch_bounds__(256)
void nlm_kernel(const float* __restrict__ pre,
                const float* __restrict__ w1,
                const float* __restrict__ b1,
                const float* __restrict__ w_out,
                const float* __restrict__ b_out,
                float* __restrict__ out) {
    __shared__ float w_lds[DBLK * WSTRIDE];   // 32.9 KB
    __shared__ float b1_lds[DBLK * 33];
    __shared__ float wo_lds[DBLK * 33];
    __shared__ float bo_lds[DBLK];

    const int tid = threadIdx.x;
    const int bx  = blockIdx.x;
    const int dt  = bx & (D_ / DBLK - 1);   // 0..255 — consecutive blocks walk d: contiguous HBM
    const int bt  = bx / (D_ / DBLK);       // 0..15
    const int d0  = dt * DBLK;
    const int b0  = bt * BBLK;

    const int d_local = tid & (DBLK - 1);
    const int bp      = tid >> 3;            // 0..31
    const int b_base  = b0 + bp * RPT;
    const int d       = d0 + d_local;

    // ---- issue pre-activation row loads FIRST (independent of LDS staging) ----
    const float* row0 = pre + ((size_t)b_base * D_ + d) * M_;
    const float* row1 = row0 + (size_t)D_ * M_;   // next b, same d
    float4 r0[M_ / 4], r1[M_ / 4];
#pragma unroll
    for (int mg = 0; mg < M_ / 4; ++mg) {
        r0[mg] = *reinterpret_cast<const float4*>(row0 + mg * 4);
        r1[mg] = *reinterpret_cast<const float4*>(row1 + mg * 4);
    }

    // ---- stage w1 tile: 8 rows of 1024 floats, coalesced float4 ----
#pragma unroll
    for (int i = 0; i < DBLK; ++i) {
        const float4 v = *reinterpret_cast<const float4*>(
            w1 + (size_t)(d0 + i) * (H_ * M_) + tid * 4);
        *reinterpret_cast<float4*>(&w_lds[i * WSTRIDE + tid * 4]) = v;
    }
    {   // b1, w_out: 256 floats each; b_out: 8
        const int di = tid >> 5, h = tid & 31;
        b1_lds[di * 33 + h] = b1[(size_t)(d0 + di) * H_ + h];
        wo_lds[di * 33 + h] = w_out[(size_t)(d0 + di) * H_ + h];
        if (tid < DBLK) bo_lds[tid] = b_out[d0 + tid];
    }
    __syncthreads();

    // ---- h-outer loop: scalar state only, no accumulator arrays ----
    const float* wrow = &w_lds[d_local * WSTRIDE];
    float s0 = 0.f, s1 = 0.f;
#pragma unroll 4
    for (int h = 0; h < H_; ++h) {
        float x0 = b1_lds[d_local * 33 + h];
        float x1 = x0;
#pragma unroll
        for (int mg = 0; mg < M_ / 4; ++mg) {
            const float4 w = *reinterpret_cast<const float4*>(wrow + h * M_ + mg * 4);
            x0 += r0[mg].x * w.x + r0[mg].y * w.y + r0[mg].z * w.z + r0[mg].w * w.w;
            x1 += r1[mg].x * w.x + r1[mg].y * w.y + r1[mg].z * w.z + r1[mg].w * w.w;
        }
        const float wo = wo_lds[d_local * 33 + h];
        s0 += gelu_exact(x0) * wo;
        s1 += gelu_exact(x1) * wo;
    }

    const float bo = bo_lds[d_local];
    out[(size_t)b_base * D_ + d]       = tanhf(s0 + bo);
    out[(size_t)(b_base + 1) * D_ + d] = tanhf(s1 + bo);
}

extern "C" void kernel_launch(void* const* d_in, const int* in_sizes, int n_in,
                              void* d_out, int out_size, void* d_ws, size_t ws_size,
                              hipStream_t stream) {
    const float* pre   = (const float*)d_in[0];
    const float* w1    = (const float*)d_in[1];
    const float* b1    = (const float*)d_in[2];
    const float* w_out = (const float*)d_in[3];
    const float* b_out = (const float*)d_in[4];
    float* out = (float*)d_out;

    const int grid = (D_ / DBLK) * (B_ / BBLK);   // 256 * 16 = 4096
    nlm_kernel<<<dim3(grid), dim3(256), 0, stream>>>(pre, w1, b1, w_out, b_out, out);
}

// Round 3
// 109.089 us; speedup vs baseline: 25.0327x; 1.0112x over previous
//
#include <hip/hip_runtime.h>
#include <math.h>

#define B_ 1024
#define D_ 2048
#define M_ 32
#define H_ 32

#define DBLK 2         // d-columns per block -> only 2 unique LDS addrs per w-read instr (2-way = free, m136)
#define BBLK 256       // b-rows per block (128 bp-threads x RPT 2)
#define RPT  2

// Abramowitz & Stegun 7.1.26, |err| <= 1.5e-7 absolute. Uses hw rcp + exp.
__device__ __forceinline__ float fast_erff(float x) {
    float ax = fabsf(x);
    float t  = __builtin_amdgcn_rcpf(1.0f + 0.3275911f * ax);
    float p  = 1.061405429f;
    p = p * t - 1.453152027f;
    p = p * t + 1.421413741f;
    p = p * t - 0.284496736f;
    p = p * t + 0.254829592f;
    float e = __expf(-ax * ax);
    float r = 1.0f - p * t * e;
    return copysignf(r, x);
}

__device__ __forceinline__ float gelu_exact(float x) {
    return 0.5f * x * (1.0f + fast_erff(x * 0.70710678118f));
}

// tanh(x) = 1 - 2/(exp(2x)+1); exp(inf)->inf->rcp->0 gives +/-1 at extremes.
__device__ __forceinline__ float fast_tanhf(float x) {
    return 1.0f - 2.0f * __builtin_amdgcn_rcpf(__expf(2.0f * x) + 1.0f);
}

__global__ __launch_bounds__(256, 4)
void nlm_kernel(const float* __restrict__ pre,
                const float* __restrict__ w1,
                const float* __restrict__ b1,
                const float* __restrict__ w_out,
                const float* __restrict__ b_out,
                float* __restrict__ out) {
    __shared__ float w_lds[DBLK * H_ * M_];   // 2 x 1024 floats = 8.2 KB
    __shared__ float b1_lds[DBLK * H_];
    __shared__ float wo_lds[DBLK * H_];
    __shared__ float bo_lds[DBLK];

    const int tid = threadIdx.x;
    const int bx  = blockIdx.x;
    const int dt  = bx & (D_ / DBLK - 1);   // 0..1023 — consecutive blocks walk d: contiguous HBM
    const int bt  = bx / (D_ / DBLK);       // 0..3
    const int d0  = dt * DBLK;
    const int b0  = bt * BBLK;

    const int d_local = tid & (DBLK - 1);   // 0..1
    const int bp      = tid >> 1;           // 0..127
    const int b_base  = b0 + bp * RPT;
    const int d       = d0 + d_local;

    // ---- issue pre-activation row loads FIRST (latency overlaps staging+sync) ----
    const float* row0 = pre + ((size_t)b_base * D_ + d) * M_;
    const float* row1 = row0 + (size_t)D_ * M_;   // next b, same d
    float4 r0[M_ / 4], r1[M_ / 4];
#pragma unroll
    for (int mg = 0; mg < M_ / 4; ++mg) {
        r0[mg] = *reinterpret_cast<const float4*>(row0 + mg * 4);
        r1[mg] = *reinterpret_cast<const float4*>(row1 + mg * 4);
    }

    // ---- stage w1 tile: 2 rows x 1024 floats = 512 float4, coalesced ----
    {
        const float4* wsrc = reinterpret_cast<const float4*>(w1) + (size_t)d0 * (H_ * M_ / 4);
#pragma unroll
        for (int i = 0; i < 2; ++i) {
            const int idx = i * 256 + tid;          // 0..511
            *reinterpret_cast<float4*>(&w_lds[idx * 4]) = wsrc[idx];
        }
        if (tid < DBLK * H_) {                      // 64 threads: b1, w_out
            const int di = tid >> 5, h = tid & 31;
            b1_lds[di * H_ + h] = b1[(size_t)(d0 + di) * H_ + h];
            wo_lds[di * H_ + h] = w_out[(size_t)(d0 + di) * H_ + h];
        }
        if (tid < DBLK) bo_lds[tid] = b_out[d0 + tid];
    }
    __syncthreads();

    // ---- h-outer loop: scalar state only ----
    const float* wrow = &w_lds[d_local * (H_ * M_)];
    float s0 = 0.f, s1 = 0.f;
#pragma unroll 4
    for (int h = 0; h < H_; ++h) {
        float x0 = b1_lds[d_local * H_ + h];
        float x1 = x0;
#pragma unroll
        for (int mg = 0; mg < M_ / 4; ++mg) {
            const float4 w = *reinterpret_cast<const float4*>(wrow + h * M_ + mg * 4);
            x0 += r0[mg].x * w.x + r0[mg].y * w.y + r0[mg].z * w.z + r0[mg].w * w.w;
            x1 += r1[mg].x * w.x + r1[mg].y * w.y + r1[mg].z * w.z + r1[mg].w * w.w;
        }
        const float wo = wo_lds[d_local * H_ + h];
        s0 += gelu_exact(x0) * wo;
        s1 += gelu_exact(x1) * wo;
    }

    const float bo = bo_lds[d_local];
    out[(size_t)b_base * D_ + d]       = fast_tanhf(s0 + bo);
    out[(size_t)(b_base + 1) * D_ + d] = fast_tanhf(s1 + bo);
}

extern "C" void kernel_launch(void* const* d_in, const int* in_sizes, int n_in,
                              void* d_out, int out_size, void* d_ws, size_t ws_size,
                              hipStream_t stream) {
    const float* pre   = (const float*)d_in[0];
    const float* w1    = (const float*)d_in[1];
    const float* b1    = (const float*)d_in[2];
    const float* w_out = (const float*)d_in[3];
    const float* b_out = (const float*)d_in[4];
    float* out = (float*)d_out;

    const int grid = (D_ / DBLK) * (B_ / BBLK);   // 1024 * 4 = 4096
    nlm_kernel<<<dim3(grid), dim3(256), 0, stream>>>(pre, w1, b1, w_out, b_out, out);
}

// Round 4
// 89.361 us; speedup vs baseline: 30.5592x; 1.2208x over previous
//
#include <hip/hip_runtime.h>
#include <math.h>

#define B_ 1024
#define D_ 2048
#define M_ 32
#define H_ 32

// Wave-per-d structure: all w1/b1/w_out/b_out traffic is wave-uniform -> SGPR
// scalar loads (s_load). Zero LDS. Each lane owns 2 b-rows held in VGPRs.

// Abramowitz & Stegun 7.1.26, |err| <= 1.5e-7 absolute. Uses hw rcp + exp.
__device__ __forceinline__ float fast_erff(float x) {
    float ax = fabsf(x);
    float t  = __builtin_amdgcn_rcpf(1.0f + 0.3275911f * ax);
    float p  = 1.061405429f;
    p = p * t - 1.453152027f;
    p = p * t + 1.421413741f;
    p = p * t - 0.284496736f;
    p = p * t + 0.254829592f;
    float e = __expf(-ax * ax);
    float r = 1.0f - p * t * e;
    return copysignf(r, x);
}

__device__ __forceinline__ float gelu_exact(float x) {
    return 0.5f * x * (1.0f + fast_erff(x * 0.70710678118f));
}

// tanh(x) = 1 - 2/(exp(2x)+1); exp(inf)->inf->rcp->0 gives +/-1 at extremes.
__device__ __forceinline__ float fast_tanhf(float x) {
    return 1.0f - 2.0f * __builtin_amdgcn_rcpf(__expf(2.0f * x) + 1.0f);
}

__global__ __launch_bounds__(256)
void nlm_kernel(const float* __restrict__ pre,
                const float* __restrict__ w1,
                const float* __restrict__ b1,
                const float* __restrict__ w_out,
                const float* __restrict__ b_out,
                float* __restrict__ out) {
    const int tid  = threadIdx.x;
    const int bx   = blockIdx.x;
    const int wid  = tid >> 6;              // 0..3: wave id -> consecutive d
    const int lane = tid & 63;
    const int dg   = bx & (D_ / 4 - 1);     // 0..511; consecutive blocks walk d -> contiguous pre
    const int bt   = bx >> 9;               // 0..7
    const int d    = dg * 4 + wid;
    const int b0   = bt * 128 + lane * 2;   // this lane's 2 b-rows

    // Wave-uniform weight pointers: readfirstlane forces scalar (s_load) path.
    const int du = __builtin_amdgcn_readfirstlane(d);
    const float* __restrict__ wr  = w1    + (size_t)du * (H_ * M_);
    const float* __restrict__ b1r = b1    + (size_t)du * H_;
    const float* __restrict__ wor = w_out + (size_t)du * H_;
    const float  bo = b_out[du];

    // ---- per-lane pre rows -> 64 VGPRs (static indexing only) ----
    const float* row0 = pre + ((size_t)b0 * D_ + du) * M_;
    const float* row1 = row0 + (size_t)D_ * M_;
    float a0[M_], a1[M_];
#pragma unroll
    for (int mg = 0; mg < M_ / 4; ++mg) {
        const float4 v0 = *reinterpret_cast<const float4*>(row0 + mg * 4);
        const float4 v1 = *reinterpret_cast<const float4*>(row1 + mg * 4);
        a0[mg * 4 + 0] = v0.x; a0[mg * 4 + 1] = v0.y; a0[mg * 4 + 2] = v0.z; a0[mg * 4 + 3] = v0.w;
        a1[mg * 4 + 0] = v1.x; a1[mg * 4 + 1] = v1.y; a1[mg * 4 + 2] = v1.z; a1[mg * 4 + 3] = v1.w;
    }

    // ---- h-outer loop; w operands come from SGPRs ----
    float s0 = 0.f, s1 = 0.f;
#pragma unroll 2
    for (int h = 0; h < H_; ++h) {
        float x0 = b1r[h];
        float x1 = x0;
#pragma unroll
        for (int m = 0; m < M_; ++m) {
            const float w = wr[h * M_ + m];     // wave-uniform -> s_load
            x0 = fmaf(a0[m], w, x0);
            x1 = fmaf(a1[m], w, x1);
        }
        const float wo = wor[h];
        s0 += gelu_exact(x0) * wo;
        s1 += gelu_exact(x1) * wo;
    }

    out[(size_t)b0 * D_ + du]       = fast_tanhf(s0 + bo);
    out[(size_t)(b0 + 1) * D_ + du] = fast_tanhf(s1 + bo);
}

extern "C" void kernel_launch(void* const* d_in, const int* in_sizes, int n_in,
                              void* d_out, int out_size, void* d_ws, size_t ws_size,
                              hipStream_t stream) {
    const float* pre   = (const float*)d_in[0];
    const float* w1    = (const float*)d_in[1];
    const float* b1    = (const float*)d_in[2];
    const float* w_out = (const float*)d_in[3];
    const float* b_out = (const float*)d_in[4];
    float* out = (float*)d_out;

    const int grid = (D_ / 4) * (B_ / 128);   // 512 * 8 = 4096 blocks of 4 waves
    nlm_kernel<<<dim3(grid), dim3(256), 0, stream>>>(pre, w1, b1, w_out, b_out, out);
}